// Round 6
// baseline (109.051 us; speedup 1.0000x reference)
//
#include <hip/hip_runtime.h>
#include <math.h>

// out[b,i,j,f] = min_{di,dj,c} ( x[b,i+di,j+dj,c] - W[di,dj,c,f] )
// x: (16,128,128,16) f32, W: (3,3,16,32) f32, out: (16,126,126,32) f32
//
// R19 = R18 with the register-residency fix actually applied.
// R18 post-mortem: asm("" : "+v") is NON-volatile = pure value op; LLVM
// sank it into the loop together with the ds_read and rematerialized
// exactly as in R17 (VGPR stayed 36, dur unchanged 47.5us).
// LDS model (confirms): re-read/body = 23 x (36 b32 x 2clk + 3 b128 x
// 8clk) = 2.2kcyc/wave x 48 waves/CU = 44us == measured. The excess VALU
// (67% busy vs 17.5us math floor) is the remat'd per-body address calc.
// Fix: asm VOLATILE -- unmodeled side effects, cannot be deleted,
// duplicated, or sunk into a loop. The 36 W dwords must stay live ->
// VGPR ~80-105 (cap 128, occupancy unchanged at 16 waves/CU).
// Main-loop LDS -> 3 b128/body (~11us pipe); VALU (~17.5us) binds.
//
// Structure (unchanged from R17):
//  * 512-thread blocks, 8 output cols (grid 16x6x16 = 1536 blocks).
//  * tile + wbuf read-only after ONE staging barrier; vm separate buffer.
//  * body: rolling 3-row window, packed-h2 min core, full-wave b16 vm
//    writes; ch-halves merged in float4 epilogue (WRITE == out size;
//    R15 lesson: never narrow-store to HBM).

#define TI 21           // output rows per block; 126 = 21*6
#define TROWS (TI + 2)  // input rows per tile (23)
#define NCOL 8          // output cols per block
#define SCOL 10         // staged cols (NCOL + 2 halo)
#define LROW 80         // tile row stride in halves (10 cols * 8 halves)
#define VCOL 68         // vm col stride in halves (64 used + 4 pad)
#define VROW (NCOL * VCOL)  // 544 halves per output row

typedef _Float16 h2 __attribute__((ext_vector_type(2)));

__device__ __forceinline__ h2 hmin2(h2 a, h2 b) {
    return __builtin_elementwise_min(a, b);  // v_pk_min_f16
}

__device__ __forceinline__ h2 pkrtz(float a, float b) {
    auto r = __builtin_amdgcn_cvt_pkrtz(a, b);  // v_cvt_pkrtz_f16_f32
    return *reinterpret_cast<h2*>(&r);
}

// min over 12 half2 of (pr[k] - w[k]) for one weight row di; consumes the
// prefetch registers directly (SSA, no copies).
__device__ __forceinline__ h2 rowmin3(const float4* pr, const h2 w[3][4]) {
    h2 t[12];
#pragma unroll
    for (int dj = 0; dj < 3; ++dj) {
        const h2* p = reinterpret_cast<const h2*>(&pr[dj]);
#pragma unroll
        for (int q = 0; q < 4; ++q)
            t[dj * 4 + q] = p[q] - w[dj][q];  // v_pk_add_f16 neg
    }
#pragma unroll
    for (int k = 0; k < 6; ++k) t[k] = hmin2(t[k], t[k + 6]);
    t[0] = hmin2(t[0], t[3]);
    t[1] = hmin2(t[1], t[4]);
    t[2] = hmin2(t[2], t[5]);
    return hmin2(hmin2(t[0], t[1]), t[2]);
}

__global__ __launch_bounds__(512, 4) void erosion_kernel(
    const float* __restrict__ x, const float* __restrict__ Wt,
    float* __restrict__ out)
{
    __shared__ __align__(16) _Float16 tile[2 * TROWS * LROW];  // 7360 B
    __shared__ __align__(16) _Float16 wbuf[2 * 2304];          // 9216 B
    __shared__ __align__(16) _Float16 vm[TI * VROW];           // 22848 B

    const int tid = threadIdx.x;
    const int f  = tid & 31;
    const int ch = (tid >> 5) & 1;   // channel half: 0 -> c 0..7, 1 -> c 8..15
    const int jt = tid >> 6;         // column in block 0..7 (wave-uniform)
    const int b  = blockIdx.z;
    const int i0 = blockIdx.y * TI;
    const int jb = blockIdx.x * NCOL;

    // ---- stage x tile: fp32 -> fp16 LDS (23 rows x 10 cols x 2 ch) ----
    // 460 chunks, one per thread (52 threads idle).
    if (tid < TROWS * 2 * SCOL) {
        const float* xg = x + (size_t)b * (128 * 128 * 16);
        int r   = tid / (2 * SCOL);
        int k   = tid % (2 * SCOL);
        int cc  = k >> 1;               // 0..9 tile column
        int ch2 = k & 1;
        int col = min(jb + cc, 127);    // clamp: feeds never-stored outputs only
        const float* src = xg + ((size_t)(i0 + r) * 128 + col) * 16 + ch2 * 8;
        float4 lo = *reinterpret_cast<const float4*>(src);
        float4 hi = *reinterpret_cast<const float4*>(src + 4);
        h2 o[4] = { pkrtz(lo.x, lo.y), pkrtz(lo.z, lo.w),
                    pkrtz(hi.x, hi.y), pkrtz(hi.z, hi.w) };
        *reinterpret_cast<float4*>(
            &tile[ch2 * (TROWS * LROW) + r * LROW + cc * 8]) =
            *reinterpret_cast<float4*>(o);
    }

    // ---- stage W packed-h2: wl[g*32 + f] = {W[.,2c,f],W[.,2c+1,f]} ----
    // g = p*8 + cpair (p = di*3+dj, cpair = c/2); W flat idx = g*64 + f.
    // 2304 h2 tasks = 4.5 rounds of 512.
    {
        h2* wl = reinterpret_cast<h2*>(wbuf);
#pragma unroll
        for (int rr = 0; rr < 4; ++rr) {
            int t  = rr * 512 + tid;
            int g  = t >> 5;
            int ff = t & 31;
            wl[t] = pkrtz(Wt[g * 64 + ff], Wt[g * 64 + 32 + ff]);
        }
        if (tid < 2304 - 2048) {
            int t  = 2048 + tid;
            int g  = t >> 5;
            int ff = t & 31;
            wl[t] = pkrtz(Wt[g * 64 + ff], Wt[g * 64 + 32 + ff]);
        }
    }

    __syncthreads();   // barrier 1: tile + wbuf read-only from here on

    // ---- read this thread's W frags ONCE: 36 conflict-free ds_read_b32,
    // then pin each value with VOLATILE empty asm. Volatile asm cannot be
    // deleted, duplicated, or sunk into the loop (execution count would
    // change), so the 36 dwords stay VGPR-resident across the main loop.
    // (R17/R18: non-volatile variant was sunk+remat'd -> 4.4KB LDS
    // re-reads/thread/loop, the 44us LDS-bandwidth wall.) ----
    h2 wh[3][3][4];
    {
        const h2* wl = reinterpret_cast<const h2*>(wbuf);
#pragma unroll
        for (int p = 0; p < 9; ++p)
#pragma unroll
            for (int q = 0; q < 4; ++q) {
                unsigned u = __builtin_bit_cast(
                    unsigned, wl[(p * 8 + ch * 4 + q) * 32 + f]);
                asm volatile("" : "+v"(u));   // pin: forces VGPR residency
                wh[p / 3][p % 3][q] = __builtin_bit_cast(h2, u);
            }
    }

    const _Float16* lb = &tile[ch * (TROWS * LROW) + jt * 8];  // row 0, col jt

    // prime depth-1 prefetch regs
    float4 pre[3];
#pragma unroll
    for (int dj = 0; dj < 3; ++dj)
        pre[dj] = *reinterpret_cast<const float4*>(lb + dj * 8);

    const _Float16 HINF = (_Float16)__builtin_huge_valf();
    h2 accB = {HINF, HINF};  // partial min for output row r-1
    h2 accC = {HINF, HINF};  // partial min for output row r-2

    // vm slot for this thread: [row][jt][ch][f] with padded col stride
    _Float16* vslot = &vm[jt * VCOL + ch * 32 + f];

    auto body = [&](int r, bool do_prefetch, bool do_vm) {
        h2 n0 = rowmin3(pre, wh[0]);
        h2 n1 = rowmin3(pre, wh[1]);
        h2 n2 = rowmin3(pre, wh[2]);

        if (do_prefetch) {
            const _Float16* ln = lb + (r + 1) * LROW;
#pragma unroll
            for (int dj = 0; dj < 3; ++dj)
                pre[dj] = *reinterpret_cast<const float4*>(ln + dj * 8);
        }

        h2 fin2 = hmin2(accC, n2);  // output row r-2 complete (this ch-half)
        accC = hmin2(accB, n1);
        accB = n0;

        if (do_vm) {
            _Float16 a = fin2[0], c = fin2[1];
            _Float16 m = a < c ? a : c;          // v_min_f16
            vslot[(r - 2) * VROW] = m;           // full-wave b16 LDS write
        }
    };

    body(0, true, false);
    body(1, true, false);
#pragma unroll
    for (int r = 2; r < TROWS - 1; ++r)   // FULL unroll: r = 2..21 literal
        body(r, true, true);
    body(TROWS - 1, false, true);         // r = 22, no prefetch

    __syncthreads();   // barrier 2: vm complete

    // ---- merge epilogue: 1344 float4 tasks, 1KB contiguous per wave ----
    // task t: row = t>>6, k = t&63, col = k>>3, q = k&7.
    // partials: ch0 at vm[row*VROW + col*VCOL + 4q..+3], ch1 at +32.
    {
        float* outb = out + (size_t)b * (126 * 126 * 32);
        auto merge = [&](int t) {
            int row = t >> 6;
            int k   = t & 63;
            int col = k >> 3;
            int q   = k & 7;
            int jj  = jb + col;
            const _Float16* base = &vm[row * VROW + col * VCOL + q * 4];
            h2 a[2], c[2];
            *reinterpret_cast<double*>(a) = *reinterpret_cast<const double*>(base);
            *reinterpret_cast<double*>(c) = *reinterpret_cast<const double*>(base + 32);
            h2 m0 = hmin2(a[0], c[0]);
            h2 m1 = hmin2(a[1], c[1]);
            float4 o = { (float)m0[0], (float)m0[1], (float)m1[0], (float)m1[1] };
            if (jj < 126)
                *reinterpret_cast<float4*>(
                    &outb[((size_t)(i0 + row) * 126 + jj) * 32 + q * 4]) = o;
        };
        merge(tid);
        merge(tid + 512);
        if (tid < TI * 64 - 1024) merge(tid + 1024);  // 320 extra tasks
    }
}

extern "C" void kernel_launch(void* const* d_in, const int* in_sizes, int n_in,
                              void* d_out, int out_size, void* d_ws, size_t ws_size,
                              hipStream_t stream) {
    const float* x  = (const float*)d_in[0];  // 16*128*128*16
    const float* Wt = (const float*)d_in[1];  // 3*3*16*32
    float* out = (float*)d_out;               // 16*126*126*32

    dim3 grid(16, 6, 16);   // 1536 blocks, 8 output cols each
    dim3 block(512);
    erosion_kernel<<<grid, block, 0, stream>>>(x, Wt, out);
}

// Round 7
// 107.347 us; speedup vs baseline: 1.0159x; 1.0159x over previous
//
#include <hip/hip_runtime.h>
#include <math.h>

// out[b,i,j,f] = min_{di,dj,c} ( x[b,i+di,j+dj,c] - W[di,dj,c,f] )
// x: (16,128,128,16) f32, W: (3,3,16,32) f32, out: (16,126,126,32) f32
//
// R20 = R17 + explicit VGPR-budget fix (the actual root cause).
// R17-R19 post-mortem: HIP __launch_bounds__(512,4)'s 2nd arg is a MIN
// waves/EU, not a max. The backend's occupancy target came from LDS
// (39.4KB -> 4 blocks/CU -> 8 waves/EU) -> VGPR budget 64. Working set
// (36 wh + 12 pre + accs + addrs ~ 58-70) >= 64, so the allocator
// remat'd the 36 wh ds_read_b32 into each unrolled body instead of
// spilling: 23 x 9216B of W re-reads per wave = the 44us LDS-BW wall.
// asm pins couldn't help (budget, not heuristic, was binding); volatile
// asm (R19) made it worse (forced order + partial pin: 60.9us).
// Fix: __attribute__((amdgpu_waves_per_eu(4,4))) pins the target to
// 4 waves/EU (16 waves/CU = measured occupancy anyway) -> budget 128 ->
// wh/pre/acc all register-resident, no remat.
// Expected: VGPR ~64-90, main-loop LDS = 3 ds_read_b128 + 1 ds_write_b16
// per body, dur -> 24-32us (VALU-issue floor ~8us math + staging+epilogue).
//
// Structure (unchanged from R17):
//  * 512-thread blocks, 8 output cols (grid 16x6x16 = 1536 blocks).
//  * tile + wbuf read-only after ONE staging barrier; vm separate buffer.
//  * body: rolling 3-row window, packed-h2 min core, full-wave b16 vm
//    writes; ch-halves merged in float4 epilogue (WRITE == out size;
//    R15 lesson: never narrow-store to HBM).

#define TI 21           // output rows per block; 126 = 21*6
#define TROWS (TI + 2)  // input rows per tile (23)
#define NCOL 8          // output cols per block
#define SCOL 10         // staged cols (NCOL + 2 halo)
#define LROW 80         // tile row stride in halves (10 cols * 8 halves)
#define VCOL 68         // vm col stride in halves (64 used + 4 pad)
#define VROW (NCOL * VCOL)  // 544 halves per output row

typedef _Float16 h2 __attribute__((ext_vector_type(2)));

__device__ __forceinline__ h2 hmin2(h2 a, h2 b) {
    return __builtin_elementwise_min(a, b);  // v_pk_min_f16
}

__device__ __forceinline__ h2 pkrtz(float a, float b) {
    auto r = __builtin_amdgcn_cvt_pkrtz(a, b);  // v_cvt_pkrtz_f16_f32
    return *reinterpret_cast<h2*>(&r);
}

// min over 12 half2 of (pr[k] - w[k]) for one weight row di; consumes the
// prefetch registers directly (SSA, no copies).
__device__ __forceinline__ h2 rowmin3(const float4* pr, const h2 w[3][4]) {
    h2 t[12];
#pragma unroll
    for (int dj = 0; dj < 3; ++dj) {
        const h2* p = reinterpret_cast<const h2*>(&pr[dj]);
#pragma unroll
        for (int q = 0; q < 4; ++q)
            t[dj * 4 + q] = p[q] - w[dj][q];  // v_pk_add_f16 neg
    }
#pragma unroll
    for (int k = 0; k < 6; ++k) t[k] = hmin2(t[k], t[k + 6]);
    t[0] = hmin2(t[0], t[3]);
    t[1] = hmin2(t[1], t[4]);
    t[2] = hmin2(t[2], t[5]);
    return hmin2(hmin2(t[0], t[1]), t[2]);
}

__global__ __launch_bounds__(512)
__attribute__((amdgpu_waves_per_eu(4, 4)))
void erosion_kernel(
    const float* __restrict__ x, const float* __restrict__ Wt,
    float* __restrict__ out)
{
    __shared__ __align__(16) _Float16 tile[2 * TROWS * LROW];  // 7360 B
    __shared__ __align__(16) _Float16 wbuf[2 * 2304];          // 9216 B
    __shared__ __align__(16) _Float16 vm[TI * VROW];           // 22848 B

    const int tid = threadIdx.x;
    const int f  = tid & 31;
    const int ch = (tid >> 5) & 1;   // channel half: 0 -> c 0..7, 1 -> c 8..15
    const int jt = tid >> 6;         // column in block 0..7 (wave-uniform)
    const int b  = blockIdx.z;
    const int i0 = blockIdx.y * TI;
    const int jb = blockIdx.x * NCOL;

    // ---- stage x tile: fp32 -> fp16 LDS (23 rows x 10 cols x 2 ch) ----
    // 460 chunks, one per thread (52 threads idle).
    if (tid < TROWS * 2 * SCOL) {
        const float* xg = x + (size_t)b * (128 * 128 * 16);
        int r   = tid / (2 * SCOL);
        int k   = tid % (2 * SCOL);
        int cc  = k >> 1;               // 0..9 tile column
        int ch2 = k & 1;
        int col = min(jb + cc, 127);    // clamp: feeds never-stored outputs only
        const float* src = xg + ((size_t)(i0 + r) * 128 + col) * 16 + ch2 * 8;
        float4 lo = *reinterpret_cast<const float4*>(src);
        float4 hi = *reinterpret_cast<const float4*>(src + 4);
        h2 o[4] = { pkrtz(lo.x, lo.y), pkrtz(lo.z, lo.w),
                    pkrtz(hi.x, hi.y), pkrtz(hi.z, hi.w) };
        *reinterpret_cast<float4*>(
            &tile[ch2 * (TROWS * LROW) + r * LROW + cc * 8]) =
            *reinterpret_cast<float4*>(o);
    }

    // ---- stage W packed-h2: wl[g*32 + f] = {W[.,2c,f],W[.,2c+1,f]} ----
    // g = p*8 + cpair (p = di*3+dj, cpair = c/2); W flat idx = g*64 + f.
    // 2304 h2 tasks = 4.5 rounds of 512.
    {
        h2* wl = reinterpret_cast<h2*>(wbuf);
#pragma unroll
        for (int rr = 0; rr < 4; ++rr) {
            int t  = rr * 512 + tid;
            int g  = t >> 5;
            int ff = t & 31;
            wl[t] = pkrtz(Wt[g * 64 + ff], Wt[g * 64 + 32 + ff]);
        }
        if (tid < 2304 - 2048) {
            int t  = 2048 + tid;
            int g  = t >> 5;
            int ff = t & 31;
            wl[t] = pkrtz(Wt[g * 64 + ff], Wt[g * 64 + 32 + ff]);
        }
    }

    __syncthreads();   // barrier 1: tile + wbuf read-only from here on

    // ---- read this thread's W frags ONCE: 36 conflict-free ds_read_b32.
    // With the 128-reg budget these stay VGPR-resident (no remat). ----
    h2 wh[3][3][4];
    {
        const h2* wl = reinterpret_cast<const h2*>(wbuf);
#pragma unroll
        for (int p = 0; p < 9; ++p)
#pragma unroll
            for (int q = 0; q < 4; ++q)
                wh[p / 3][p % 3][q] = wl[(p * 8 + ch * 4 + q) * 32 + f];
    }

    const _Float16* lb = &tile[ch * (TROWS * LROW) + jt * 8];  // row 0, col jt

    // prime depth-1 prefetch regs
    float4 pre[3];
#pragma unroll
    for (int dj = 0; dj < 3; ++dj)
        pre[dj] = *reinterpret_cast<const float4*>(lb + dj * 8);

    const _Float16 HINF = (_Float16)__builtin_huge_valf();
    h2 accB = {HINF, HINF};  // partial min for output row r-1
    h2 accC = {HINF, HINF};  // partial min for output row r-2

    // vm slot for this thread: [row][jt][ch][f] with padded col stride
    _Float16* vslot = &vm[jt * VCOL + ch * 32 + f];

    auto body = [&](int r, bool do_prefetch, bool do_vm) {
        h2 n0 = rowmin3(pre, wh[0]);
        h2 n1 = rowmin3(pre, wh[1]);
        h2 n2 = rowmin3(pre, wh[2]);

        if (do_prefetch) {
            const _Float16* ln = lb + (r + 1) * LROW;
#pragma unroll
            for (int dj = 0; dj < 3; ++dj)
                pre[dj] = *reinterpret_cast<const float4*>(ln + dj * 8);
        }

        h2 fin2 = hmin2(accC, n2);  // output row r-2 complete (this ch-half)
        accC = hmin2(accB, n1);
        accB = n0;

        if (do_vm) {
            _Float16 a = fin2[0], c = fin2[1];
            _Float16 m = a < c ? a : c;          // v_min_f16
            vslot[(r - 2) * VROW] = m;           // full-wave b16 LDS write
        }
    };

    body(0, true, false);
    body(1, true, false);
#pragma unroll
    for (int r = 2; r < TROWS - 1; ++r)   // FULL unroll: r = 2..21 literal
        body(r, true, true);
    body(TROWS - 1, false, true);         // r = 22, no prefetch

    __syncthreads();   // barrier 2: vm complete

    // ---- merge epilogue: 1344 float4 tasks, 1KB contiguous per wave ----
    // task t: row = t>>6, k = t&63, col = k>>3, q = k&7.
    // partials: ch0 at vm[row*VROW + col*VCOL + 4q..+3], ch1 at +32.
    {
        float* outb = out + (size_t)b * (126 * 126 * 32);
        auto merge = [&](int t) {
            int row = t >> 6;
            int k   = t & 63;
            int col = k >> 3;
            int q   = k & 7;
            int jj  = jb + col;
            const _Float16* base = &vm[row * VROW + col * VCOL + q * 4];
            h2 a[2], c[2];
            *reinterpret_cast<double*>(a) = *reinterpret_cast<const double*>(base);
            *reinterpret_cast<double*>(c) = *reinterpret_cast<const double*>(base + 32);
            h2 m0 = hmin2(a[0], c[0]);
            h2 m1 = hmin2(a[1], c[1]);
            float4 o = { (float)m0[0], (float)m0[1], (float)m1[0], (float)m1[1] };
            if (jj < 126)
                *reinterpret_cast<float4*>(
                    &outb[((size_t)(i0 + row) * 126 + jj) * 32 + q * 4]) = o;
        };
        merge(tid);
        merge(tid + 512);
        if (tid < TI * 64 - 1024) merge(tid + 1024);  // 320 extra tasks
    }
}

extern "C" void kernel_launch(void* const* d_in, const int* in_sizes, int n_in,
                              void* d_out, int out_size, void* d_ws, size_t ws_size,
                              hipStream_t stream) {
    const float* x  = (const float*)d_in[0];  // 16*128*128*16
    const float* Wt = (const float*)d_in[1];  // 3*3*16*32
    float* out = (float*)d_out;               // 16*126*126*32

    dim3 grid(16, 6, 16);   // 1536 blocks, 8 output cols each
    dim3 block(512);
    erosion_kernel<<<grid, block, 0, stream>>>(x, Wt, out);
}

// Round 8
// 106.856 us; speedup vs baseline: 1.0205x; 1.0046x over previous
//
#include <hip/hip_runtime.h>
#include <math.h>

// out[b,i,j,f] = min_{di,dj,c} ( x[b,i+di,j+dj,c] - W[di,dj,c,f] )
// x: (16,128,128,16) f32, W: (3,3,16,32) f32, out: (16,126,126,32) f32
//
// R21 = R20 + W reads forced into registers via a volatile asm ds_read
// block (remat-proof).
// R17-R20 post-mortem: LLVM's spiller treats loop-invariant-address
// ds_reads as trivially rematerializable and ALWAYS re-reads the 36 W
// dwords per unrolled body, no matter the VGPR budget (hints: launch_
// bounds min-arg R17/18, asm pins R18/19, waves_per_eu(4,4) R20 -- all
// left dur at ~47.5us). LDS pipe model fits exactly: 23 bodies x (36 b32
// x 2clk + 3 b128 x 8clk + write) = 2254 clk/wave x 48 waves/CU = 45us.
// Fix: ONE asm volatile block = 9 x ds_read_b128 (W restaged tap-
// contiguous: byte addr p*1024 + ch*512 + f*16, linear per wave) +
// s_waitcnt lgkmcnt(0), "memory" clobber. Volatile asm can't be sunk/
// duplicated; outputs are opaque SSA -> must stay VGPR-resident.
// waves_per_eu(4,4) is now ESSENTIAL: budget 128 prevents scratch spill
// of the pinned values (asm outputs can't be remat'd, only spilled).
// Main loop: 3 ds_read_b128 + 1 ds_write_b16 + ~72 pk-ops per body
// -> ~13us LDS + ~10us VALU, overlapped. Predicted 20-30us.
//
// Structure (otherwise unchanged from R20):
//  * 512-thread blocks, 8 output cols (grid 16x6x16 = 1536 blocks).
//  * tile + wbuf read-only after ONE staging barrier; vm separate buffer.
//  * body: rolling 3-row window, packed-h2 min core, full-wave b16 vm
//    writes; ch-halves merged in float4 epilogue (WRITE == out size;
//    R15 lesson: never narrow-store to HBM).

#define TI 21           // output rows per block; 126 = 21*6
#define TROWS (TI + 2)  // input rows per tile (23)
#define NCOL 8          // output cols per block
#define SCOL 10         // staged cols (NCOL + 2 halo)
#define LROW 80         // tile row stride in halves (10 cols * 8 halves)
#define VCOL 68         // vm col stride in halves (64 used + 4 pad)
#define VROW (NCOL * VCOL)  // 544 halves per output row

typedef _Float16 h2 __attribute__((ext_vector_type(2)));

__device__ __forceinline__ h2 hmin2(h2 a, h2 b) {
    return __builtin_elementwise_min(a, b);  // v_pk_min_f16
}

__device__ __forceinline__ h2 pkrtz(float a, float b) {
    auto r = __builtin_amdgcn_cvt_pkrtz(a, b);  // v_cvt_pkrtz_f16_f32
    return *reinterpret_cast<h2*>(&r);
}

// min over 12 half2 of (pr[k] - w[k]) for one weight row di; consumes the
// prefetch registers directly (SSA, no copies).
__device__ __forceinline__ h2 rowmin3(const float4* pr, const h2* w) {
    h2 t[12];
#pragma unroll
    for (int dj = 0; dj < 3; ++dj) {
        const h2* p = reinterpret_cast<const h2*>(&pr[dj]);
#pragma unroll
        for (int q = 0; q < 4; ++q)
            t[dj * 4 + q] = p[q] - w[dj * 4 + q];  // v_pk_add_f16 neg
    }
#pragma unroll
    for (int k = 0; k < 6; ++k) t[k] = hmin2(t[k], t[k + 6]);
    t[0] = hmin2(t[0], t[3]);
    t[1] = hmin2(t[1], t[4]);
    t[2] = hmin2(t[2], t[5]);
    return hmin2(hmin2(t[0], t[1]), t[2]);
}

__global__ __launch_bounds__(512)
__attribute__((amdgpu_waves_per_eu(4, 4)))
void erosion_kernel(
    const float* __restrict__ x, const float* __restrict__ Wt,
    float* __restrict__ out)
{
    __shared__ __align__(16) _Float16 tile[2 * TROWS * LROW];  // 7360 B
    __shared__ __align__(16) _Float16 wbuf[2 * 2304];          // 9216 B
    __shared__ __align__(16) _Float16 vm[TI * VROW];           // 22848 B

    const int tid = threadIdx.x;
    const int f  = tid & 31;
    const int ch = (tid >> 5) & 1;   // channel half: 0 -> c 0..7, 1 -> c 8..15
    const int jt = tid >> 6;         // column in block 0..7 (wave-uniform)
    const int b  = blockIdx.z;
    const int i0 = blockIdx.y * TI;
    const int jb = blockIdx.x * NCOL;

    // ---- stage x tile: fp32 -> fp16 LDS (23 rows x 10 cols x 2 ch) ----
    // 460 chunks, one per thread (52 threads idle).
    if (tid < TROWS * 2 * SCOL) {
        const float* xg = x + (size_t)b * (128 * 128 * 16);
        int r   = tid / (2 * SCOL);
        int k   = tid % (2 * SCOL);
        int cc  = k >> 1;               // 0..9 tile column
        int ch2 = k & 1;
        int col = min(jb + cc, 127);    // clamp: feeds never-stored outputs only
        const float* src = xg + ((size_t)(i0 + r) * 128 + col) * 16 + ch2 * 8;
        float4 lo = *reinterpret_cast<const float4*>(src);
        float4 hi = *reinterpret_cast<const float4*>(src + 4);
        h2 o[4] = { pkrtz(lo.x, lo.y), pkrtz(lo.z, lo.w),
                    pkrtz(hi.x, hi.y), pkrtz(hi.z, hi.w) };
        *reinterpret_cast<float4*>(
            &tile[ch2 * (TROWS * LROW) + r * LROW + cc * 8]) =
            *reinterpret_cast<float4*>(o);
    }

    // ---- stage W packed-h2, TAP-CONTIGUOUS layout ----
    // wl2 h2-index p*256 + ch*128 + f*4 + q  (p = di*3+dj tap, q = cpair
    // within ch-half) = {W[p, ch*8+2q, f], W[p, ch*8+2q+1, f]}.
    // Per (tap,ch,f) the 4 h2 are 16B contiguous -> one ds_read_b128.
    // Source decomposition keeps global reads coalesced (g*64+ff).
    {
        h2* wl = reinterpret_cast<h2*>(wbuf);
        auto wstage = [&](int t) {
            int g  = t >> 5;           // p*8 + cpair
            int ff = t & 31;
            int p  = g >> 3;
            int cp = g & 7;            // ch2*4 + q
            int ch2 = cp >> 2;
            int q  = cp & 3;
            wl[p * 256 + ch2 * 128 + ff * 4 + q] =
                pkrtz(Wt[g * 64 + ff], Wt[g * 64 + 32 + ff]);
        };
#pragma unroll
        for (int rr = 0; rr < 4; ++rr) wstage(rr * 512 + tid);
        if (tid < 2304 - 2048) wstage(2048 + tid);
    }

    __syncthreads();   // barrier 1: tile + wbuf read-only from here on

    // ---- read this thread's W frags ONCE via volatile asm: 9 x
    // ds_read_b128, conflict-free (1024B linear per tap per wave), with
    // the waitcnt inside the block. Outputs are opaque SSA values ->
    // cannot be rematerialized into the main loop (the R17-R20 wall). ----
    float4 w9[9];
    {
        unsigned wa = (unsigned)(uintptr_t)(&wbuf[0]) + ch * 512 + f * 16;
        asm volatile(
            "ds_read_b128 %0, %9 offset:0\n\t"
            "ds_read_b128 %1, %9 offset:1024\n\t"
            "ds_read_b128 %2, %9 offset:2048\n\t"
            "ds_read_b128 %3, %9 offset:3072\n\t"
            "ds_read_b128 %4, %9 offset:4096\n\t"
            "ds_read_b128 %5, %9 offset:5120\n\t"
            "ds_read_b128 %6, %9 offset:6144\n\t"
            "ds_read_b128 %7, %9 offset:7168\n\t"
            "ds_read_b128 %8, %9 offset:8192\n\t"
            "s_waitcnt lgkmcnt(0)"
            : "=&v"(w9[0]), "=&v"(w9[1]), "=&v"(w9[2]), "=&v"(w9[3]),
              "=&v"(w9[4]), "=&v"(w9[5]), "=&v"(w9[6]), "=&v"(w9[7]),
              "=&v"(w9[8])
            : "v"(wa)
            : "memory");
    }
    const h2* wh0 = reinterpret_cast<const h2*>(&w9[0]);  // taps 0..2 (di=0)
    const h2* wh1 = reinterpret_cast<const h2*>(&w9[3]);  // taps 3..5 (di=1)
    const h2* wh2 = reinterpret_cast<const h2*>(&w9[6]);  // taps 6..8 (di=2)

    const _Float16* lb = &tile[ch * (TROWS * LROW) + jt * 8];  // row 0, col jt

    // prime depth-1 prefetch regs
    float4 pre[3];
#pragma unroll
    for (int dj = 0; dj < 3; ++dj)
        pre[dj] = *reinterpret_cast<const float4*>(lb + dj * 8);

    const _Float16 HINF = (_Float16)__builtin_huge_valf();
    h2 accB = {HINF, HINF};  // partial min for output row r-1
    h2 accC = {HINF, HINF};  // partial min for output row r-2

    // vm slot for this thread: [row][jt][ch][f] with padded col stride
    _Float16* vslot = &vm[jt * VCOL + ch * 32 + f];

    auto body = [&](int r, bool do_prefetch, bool do_vm) {
        h2 n0 = rowmin3(pre, wh0);
        h2 n1 = rowmin3(pre, wh1);
        h2 n2 = rowmin3(pre, wh2);

        if (do_prefetch) {
            const _Float16* ln = lb + (r + 1) * LROW;
#pragma unroll
            for (int dj = 0; dj < 3; ++dj)
                pre[dj] = *reinterpret_cast<const float4*>(ln + dj * 8);
        }

        h2 fin2 = hmin2(accC, n2);  // output row r-2 complete (this ch-half)
        accC = hmin2(accB, n1);
        accB = n0;

        if (do_vm) {
            _Float16 a = fin2[0], c = fin2[1];
            _Float16 m = a < c ? a : c;          // v_min_f16
            vslot[(r - 2) * VROW] = m;           // full-wave b16 LDS write
        }
    };

    body(0, true, false);
    body(1, true, false);
#pragma unroll
    for (int r = 2; r < TROWS - 1; ++r)   // FULL unroll: r = 2..21 literal
        body(r, true, true);
    body(TROWS - 1, false, true);         // r = 22, no prefetch

    __syncthreads();   // barrier 2: vm complete

    // ---- merge epilogue: 1344 float4 tasks, 1KB contiguous per wave ----
    // task t: row = t>>6, k = t&63, col = k>>3, q = k&7.
    // partials: ch0 at vm[row*VROW + col*VCOL + 4q..+3], ch1 at +32.
    {
        float* outb = out + (size_t)b * (126 * 126 * 32);
        auto merge = [&](int t) {
            int row = t >> 6;
            int k   = t & 63;
            int col = k >> 3;
            int q   = k & 7;
            int jj  = jb + col;
            const _Float16* base = &vm[row * VROW + col * VCOL + q * 4];
            h2 a[2], c[2];
            *reinterpret_cast<double*>(a) = *reinterpret_cast<const double*>(base);
            *reinterpret_cast<double*>(c) = *reinterpret_cast<const double*>(base + 32);
            h2 m0 = hmin2(a[0], c[0]);
            h2 m1 = hmin2(a[1], c[1]);
            float4 o = { (float)m0[0], (float)m0[1], (float)m1[0], (float)m1[1] };
            if (jj < 126)
                *reinterpret_cast<float4*>(
                    &outb[((size_t)(i0 + row) * 126 + jj) * 32 + q * 4]) = o;
        };
        merge(tid);
        merge(tid + 512);
        if (tid < TI * 64 - 1024) merge(tid + 1024);  // 320 extra tasks
    }
}

extern "C" void kernel_launch(void* const* d_in, const int* in_sizes, int n_in,
                              void* d_out, int out_size, void* d_ws, size_t ws_size,
                              hipStream_t stream) {
    const float* x  = (const float*)d_in[0];  // 16*128*128*16
    const float* Wt = (const float*)d_in[1];  // 3*3*16*32
    float* out = (float*)d_out;               // 16*126*126*32

    dim3 grid(16, 6, 16);   // 1536 blocks, 8 output cols each
    dim3 block(512);
    erosion_kernel<<<grid, block, 0, stream>>>(x, Wt, out);
}